// Round 10
// baseline (309.116 us; speedup 1.0000x reference)
//
#include <hip/hip_runtime.h>
#include <hip/hip_cooperative_groups.h>
#include <stdint.h>

typedef __bf16 bf16x8 __attribute__((ext_vector_type(8)));
typedef float  f32x4  __attribute__((ext_vector_type(4)));
typedef unsigned short u16x8 __attribute__((ext_vector_type(8)));

typedef __attribute__((address_space(3))) void lds_void;
typedef __attribute__((address_space(1))) const void gbl_cvoid;

__device__ __forceinline__ unsigned short f2bf(float f) {
  union { float f; uint32_t u; } v; v.f = f;
  return (unsigned short)((v.u + 0x7FFFu + ((v.u >> 16) & 1u)) >> 16);
}

// One cooperative kernel, 256 blocks x 512 threads, 1 block/CU.
// Phase 0: cvt(x,w1,w2)+weff gather. Phase 1: t1 = x@w1^T (64x64 tiles,
// intra-block split-K x2). Phase 2: main GEMM (256x256 tile, 2-phase dbuf,
// counted vmcnt). grid.sync() between phases (device-scope fence).
__global__ __launch_bounds__(512, 2) void mega_kernel(
    const float* __restrict__ x,
    const float* __restrict__ weight,
    const float* __restrict__ w1,
    const float* __restrict__ w2,
    const float* __restrict__ bias,
    const int* __restrict__ flat,
    unsigned short* __restrict__ xb,
    unsigned short* __restrict__ w1b,
    unsigned short* __restrict__ w2b,
    unsigned short* __restrict__ weff,
    unsigned short* __restrict__ t1,
    float* __restrict__ out) {
  __shared__ __align__(16) char smem[131072];
  cooperative_groups::grid_group grid = cooperative_groups::this_grid();
  const int tid = threadIdx.x;
  const int bid = blockIdx.x;

  // ================= phase 0: prep =================
  {
    const int NX = (4096 * 4096) / 8;   // 2097152
    const int NW = (256 * 4096) / 8;    // 131072
    const int NF = (20480 * 256) / 8;   // 655360
    const int total = NX + 2 * NW + NF; // 3014656 = 23 * 131072
    for (int i = bid * 512 + tid; i < total; i += 256 * 512) {
      const float* src;
      unsigned short* dst;
      if (i < NX) {
        src = x + (size_t)i * 8;  dst = xb + (size_t)i * 8;
      } else if (i < NX + NW) {
        int k = i - NX;
        src = w1 + (size_t)k * 8; dst = w1b + (size_t)k * 8;
      } else if (i < NX + 2 * NW) {
        int k = i - NX - NW;
        src = w2 + (size_t)k * 8; dst = w2b + (size_t)k * 8;
      } else {
        int widx = i - NX - 2 * NW;           // 0..655359
        int row = widx >> 5;                  // 0..20479
        int c8  = (widx & 31) << 3;
        int ob = row / 1280;
        int t  = row - ob * 1280;
        int s  = t >> 8;
        int r  = t & 255;
        int f  = flat[ob * 5 + s];
        int q  = f / 5;
        int jj = f - q * 5;
        int k  = (jj << 8) + r;
        int i2 = k / 5;
        int a  = k - i2 * 5;
        src = weight + ((size_t)((q << 8) + i2) * 5 + a) * 256 + c8;
        dst = weff + (size_t)row * 256 + c8;
      }
      f32x4 va = ((const f32x4*)src)[0], vb = ((const f32x4*)src)[1];
      u16x8 o;
      o[0] = f2bf(va[0]); o[1] = f2bf(va[1]); o[2] = f2bf(va[2]); o[3] = f2bf(va[3]);
      o[4] = f2bf(vb[0]); o[5] = f2bf(vb[1]); o[6] = f2bf(vb[2]); o[7] = f2bf(vb[3]);
      *(u16x8*)dst = o;
    }
  }
  grid.sync();

  // ================= phase 1: t1 = x @ w1^T =================
  {
    const int lane = tid & 63, w = tid >> 6;
    const int half = w >> 2, hw = w & 3;
    const int wr = hw >> 1, wc = hw & 1;
    const int lr = lane & 15, lk = lane >> 4, lr7 = lr & 7;
    const int row0 = (bid >> 2) << 6, col0 = (bid & 3) << 6;
    const int htid = tid & 255;
    const int rr = htid >> 3;                   // 0..31
    const int csw = (htid & 7) ^ (rr & 7);
    const int cs0 = (lk ^ lr7) << 4, cs1 = ((4 | lk) ^ lr7) << 4;
    const int aRow = ((wr << 5) + lr) << 7;
    const int bRow = ((wc << 5) + lr) << 7;
    char* hbase = smem + (half << 15);

    const unsigned short* As = xb  + (size_t)(row0 + rr) * 4096 + (half << 11) + csw * 8;
    const unsigned short* Bs = w1b + (size_t)(col0 + rr) * 4096 + (half << 11) + csw * 8;

    f32x4 acc[2][2];
#pragma unroll
    for (int m = 0; m < 2; ++m)
#pragma unroll
      for (int n = 0; n < 2; ++n) acc[m][n] = (f32x4){0.f, 0.f, 0.f, 0.f};

    auto STAGE = [&](int t) {
      char* d = hbase + ((t & 1) << 14) + (htid << 4);
      const unsigned short* a = As + (t << 6);
      const unsigned short* bp = Bs + (t << 6);
      __builtin_amdgcn_global_load_lds((gbl_cvoid*)a, (lds_void*)d, 16, 0, 0);
      __builtin_amdgcn_global_load_lds((gbl_cvoid*)(a + (size_t)32 * 4096), (lds_void*)(d + 4096), 16, 0, 0);
      __builtin_amdgcn_global_load_lds((gbl_cvoid*)bp, (lds_void*)(d + 8192), 16, 0, 0);
      __builtin_amdgcn_global_load_lds((gbl_cvoid*)(bp + (size_t)32 * 4096), (lds_void*)(d + 12288), 16, 0, 0);
    };

    STAGE(0);
#pragma unroll 1
    for (int t = 0; t < 32; ++t) {
      if (t < 31) {
        STAGE(t + 1);
        asm volatile("s_waitcnt vmcnt(4)" ::: "memory");
      } else {
        asm volatile("s_waitcnt vmcnt(0)" ::: "memory");
      }
      __builtin_amdgcn_s_barrier();
      const char* Ab = hbase + ((t & 1) << 14);
      const char* Bb = Ab + 8192;
      bf16x8 aq[2][2], bq[2][2];
#pragma unroll
      for (int m = 0; m < 2; ++m) {
        aq[m][0] = *(const bf16x8*)(Ab + aRow + m * 2048 + cs0);
        aq[m][1] = *(const bf16x8*)(Ab + aRow + m * 2048 + cs1);
        bq[m][0] = *(const bf16x8*)(Bb + bRow + m * 2048 + cs0);
        bq[m][1] = *(const bf16x8*)(Bb + bRow + m * 2048 + cs1);
      }
#pragma unroll
      for (int m = 0; m < 2; ++m)
#pragma unroll
        for (int n = 0; n < 2; ++n) {
          acc[m][n] = __builtin_amdgcn_mfma_f32_16x16x32_bf16(aq[m][0], bq[n][0], acc[m][n], 0, 0, 0);
          acc[m][n] = __builtin_amdgcn_mfma_f32_16x16x32_bf16(aq[m][1], bq[n][1], acc[m][n], 0, 0, 0);
        }
      asm volatile("" ::: "memory");
      __builtin_amdgcn_s_barrier();
    }

    __syncthreads();
    if (half == 1) {
#pragma unroll
      for (int m = 0; m < 2; ++m)
#pragma unroll
        for (int n = 0; n < 2; ++n)
          *(f32x4*)(smem + ((((hw << 2) + (m << 1) + n) << 6) + lane) * 16) = acc[m][n];
    }
    __syncthreads();
    if (half == 0) {
#pragma unroll
      for (int m = 0; m < 2; ++m)
#pragma unroll
        for (int n = 0; n < 2; ++n) {
          f32x4 p = *(const f32x4*)(smem + ((((hw << 2) + (m << 1) + n) << 6) + lane) * 16);
          int row = row0 + (wr << 5) + (m << 4) + (lk << 2);
          int col = col0 + (wc << 5) + (n << 4) + lr;
#pragma unroll
          for (int jj = 0; jj < 4; ++jj)
            t1[(size_t)(row + jj) * 256 + col] = f2bf(acc[m][n][jj] + p[jj]);
        }
    }
  }
  grid.sync();

  // ================= phase 2: main GEMM =================
  {
    const int lane = tid & 63;
    const int w    = tid >> 6;                   // 0..7
    const int wr   = w >> 2, wc = w & 3;         // wave = 128 rows x 64 cols
    const int lr   = lane & 15, lk = lane >> 4, lr7 = lr & 7;

    int swz = ((bid & 7) << 5) | (bid >> 3);     // bijective: 256 % 8 == 0
    const int bx = swz >> 4, by = swz & 15;
    const int row0 = bx << 8, col0 = by << 8;    // ob == by

    const int rr0 = tid >> 3;                    // 0..63
    const int csw = (tid & 7) ^ (rr0 & 7);

    const int base5 = by * 5;
    const int cA1 = (flat[base5 + 0] / 5) << 8;
    const int cA2 = (flat[base5 + 1] / 5) << 8;
    const int cA3 = (flat[base5 + 2] / 5) << 8;
    const int cA4 = (flat[base5 + 3] / 5) << 8;
    const int cA5 = (flat[base5 + 4] / 5) << 8;

    f32x4 acc[8][4];
#pragma unroll
    for (int m = 0; m < 8; ++m)
#pragma unroll
      for (int n = 0; n < 4; ++n) acc[m][n] = (f32x4){0.f, 0.f, 0.f, 0.f};

    auto stage = [&](int T) {
      int s = T >> 2, k0 = (T & 3) << 6;
      char* dstA = smem + ((T & 1) << 16) + (tid << 4);
      char* dstB = dstA + 32768;
      const unsigned short* Ab;
      int Astr;
      if (s == 0) { Ab = t1 + (size_t)row0 * 256; Astr = 256; }
      else {
        int colA = (s == 1) ? cA1 : (s == 2) ? cA2 : (s == 3) ? cA3
                 : (s == 4) ? cA4 : cA5;
        Ab = xb + (size_t)row0 * 4096 + colA; Astr = 4096;
      }
      const unsigned short* Bb = (s == 0)
          ? (w2b + (size_t)col0 * 256)
          : (weff + ((size_t)(base5 + s - 1) << 16));
#pragma unroll
      for (int g = 0; g < 4; ++g) {
        int r = (g << 6) + rr0;
        const unsigned short* srcA = Ab + (size_t)r * Astr + k0 + csw * 8;
        __builtin_amdgcn_global_load_lds((gbl_cvoid*)srcA,
            (lds_void*)(dstA + (g << 13)), 16, 0, 0);
      }
#pragma unroll
      for (int g = 0; g < 4; ++g) {
        int r = (g << 6) + rr0;
        const unsigned short* srcB = Bb + (size_t)r * 256 + k0 + csw * 8;
        __builtin_amdgcn_global_load_lds((gbl_cvoid*)srcB,
            (lds_void*)(dstB + (g << 13)), 16, 0, 0);
      }
    };

    stage(0);
#pragma unroll 1
    for (int t = 0; t < 24; ++t) {
      if (t < 23) {
        stage(t + 1);
        asm volatile("s_waitcnt vmcnt(8)" ::: "memory");   // tile t landed
      } else {
        asm volatile("s_waitcnt vmcnt(0)" ::: "memory");
      }
      __builtin_amdgcn_s_barrier();
      const char* Ab = smem + ((t & 1) << 16);
      const char* Bb = Ab + 32768;
      bf16x8 bq[4][2];
#pragma unroll
      for (int n = 0; n < 4; ++n) {
        int row = (wc << 6) + (n << 4) + lr;
        bq[n][0] = *(const bf16x8*)(Bb + row * 128 + ((lk ^ lr7) << 4));
        bq[n][1] = *(const bf16x8*)(Bb + row * 128 + (((4 | lk) ^ lr7) << 4));
      }
#pragma unroll
      for (int m = 0; m < 8; ++m) {
        int row = (wr << 7) + (m << 4) + lr;
        bf16x8 a0 = *(const bf16x8*)(Ab + row * 128 + ((lk ^ lr7) << 4));
        bf16x8 a1 = *(const bf16x8*)(Ab + row * 128 + (((4 | lk) ^ lr7) << 4));
#pragma unroll
        for (int n = 0; n < 4; ++n)
          acc[m][n] = __builtin_amdgcn_mfma_f32_16x16x32_bf16(a0, bq[n][0], acc[m][n], 0, 0, 0);
#pragma unroll
        for (int n = 0; n < 4; ++n)
          acc[m][n] = __builtin_amdgcn_mfma_f32_16x16x32_bf16(a1, bq[n][1], acc[m][n], 0, 0, 0);
      }
      asm volatile("" ::: "memory");
      __builtin_amdgcn_s_barrier();
    }

#pragma unroll
    for (int n = 0; n < 4; ++n) {
      int col = col0 + (wc << 6) + (n << 4) + lr;
      float bv = bias[col];
#pragma unroll
      for (int m = 0; m < 8; ++m) {
        int row = row0 + (wr << 7) + (m << 4) + (lk << 2);
#pragma unroll
        for (int jj = 0; jj < 4; ++jj)
          out[(size_t)(row + jj) * 4096 + col] = acc[m][n][jj] + bv;
      }
    }
  }
}

extern "C" void kernel_launch(void* const* d_in, const int* in_sizes, int n_in,
                              void* d_out, int out_size, void* d_ws, size_t ws_size,
                              hipStream_t stream) {
  const float* x      = (const float*)d_in[0];
  const float* weight = (const float*)d_in[1];
  const float* w1     = (const float*)d_in[2];
  const float* w2     = (const float*)d_in[3];
  const float* bias   = (const float*)d_in[4];
  const int*   flat   = (const int*)d_in[5];
  float* out = (float*)d_out;

  char* ws = (char*)d_ws;
  unsigned short* xb   = (unsigned short*)(ws);                  // 32 MiB
  unsigned short* w1b  = (unsigned short*)(ws + 33554432);       // 2 MiB
  unsigned short* w2b  = (unsigned short*)(ws + 35651584);       // 2 MiB
  unsigned short* weff = (unsigned short*)(ws + 37748736);       // 10 MiB
  unsigned short* t1   = (unsigned short*)(ws + 48234496);       // 2 MiB

  void* args[] = {(void*)&x, (void*)&weight, (void*)&w1, (void*)&w2,
                  (void*)&bias, (void*)&flat, (void*)&xb, (void*)&w1b,
                  (void*)&w2b, (void*)&weff, (void*)&t1, (void*)&out};
  hipLaunchCooperativeKernel((void*)mega_kernel, dim3(256), dim3(512),
                             args, 0, stream);
}